// Round 19
// baseline (548.838 us; speedup 1.0000x reference)
//
#include <hip/hip_runtime.h>
#include <hip/hip_fp16.h>

#define NSEQ 8192
#define DIM  512

typedef _Float16 f16;
typedef _Float16 f16x8 __attribute__((ext_vector_type(8)));
typedef _Float16 f16x4 __attribute__((ext_vector_type(4)));
typedef float    f32x4 __attribute__((ext_vector_type(4)));

// S^T fragment layout (16x16 f32, C-native): frag(qt, jt) at
//   ST + ((size_t)qt*512 + jt)*256 ; lane l's 4 values at +l*4
//   value (j = jt*16 + (l>>4)*4 + r, q = qt*16 + (l&15))
// XhTf layout (k-permuted to match B built from two S^T frags):
//   element (d, j): frag = (d>>4)*256 + (j>>5); within: lane = ((j>>2)&3)*16
//   + (d&15); slot e = (j&3) | (((j>>4)&1)<<2); offset frag*512 + lane*8 + e.
// qkt/proj staging: R13 variant (fastest of 4 measured): XOR-swizzled
//   row-major LDS, reg-staged, loads at top of step.
// pvx4 v2: depth-2 ST register prefetch (4 named buffer sets, unroll x4),
//   row-max fused into prologue (smax2 kernel deleted).

// ---------------------------------------------------------------------------
// X (fp32) -> Xh + Xl (f16 hi/lo split), row-major.
// ---------------------------------------------------------------------------
__global__ __launch_bounds__(256) void k_splitx(const float* __restrict__ X,
                                                f16* __restrict__ Xh,
                                                f16* __restrict__ Xl)
{
  const size_t idx = (size_t)blockIdx.x * 256 + threadIdx.x;
  f32x4 v = *(const f32x4*)(X + idx * 4);
  f16x4 h, l;
#pragma unroll
  for (int i = 0; i < 4; ++i) {
    h[i] = (f16)v[i];
    l[i] = (f16)(v[i] - (float)h[i]);
  }
  *(f16x4*)(Xh + idx * 4) = h;
  *(f16x4*)(Xl + idx * 4) = l;
}

// ---------------------------------------------------------------------------
// Both W's (512x512 fp32) -> Wt^T split, z selects Wq/Wk.
// ---------------------------------------------------------------------------
__global__ __launch_bounds__(256) void k_splitwt2(
    const float* __restrict__ Wq, const float* __restrict__ Wk,
    f16* __restrict__ Thq, f16* __restrict__ Tlq,
    f16* __restrict__ Thk, f16* __restrict__ Tlk)
{
  __shared__ float T[64][65];
  const int tid = threadIdx.x;
  const int k0 = blockIdx.x * 64;
  const int c0 = blockIdx.y * 64;
  const float* W = blockIdx.z ? Wk : Wq;
  f16* Th = blockIdx.z ? Thk : Thq;
  f16* Tl = blockIdx.z ? Tlk : Tlq;
#pragma unroll
  for (int e = 0; e < 16; ++e) {
    int idx = tid + e * 256;
    T[idx >> 6][idx & 63] = W[(size_t)(k0 + (idx >> 6)) * DIM + c0 + (idx & 63)];
  }
  __syncthreads();
#pragma unroll
  for (int e = 0; e < 16; ++e) {
    int idx = tid + e * 256;
    int cc = idx >> 6, kk = idx & 63;
    float v = T[kk][cc];
    f16 h = (f16)v;
    Th[(size_t)(c0 + cc) * DIM + k0 + kk] = h;
    Tl[(size_t)(c0 + cc) * DIM + k0 + kk] = (f16)(v - (float)h);
  }
}

// ---------------------------------------------------------------------------
// X -> XhTf: k-permuted frag-tiled V^T (rows = d, k-cols = j).
// ---------------------------------------------------------------------------
__global__ __launch_bounds__(256) void k_xt2(const float* __restrict__ X,
                                             f16* __restrict__ XhTf)
{
  __shared__ float T[64][65];
  const int tid = threadIdx.x;
  const int j0 = blockIdx.x * 64;
  const int d0 = blockIdx.y * 64;
#pragma unroll
  for (int e = 0; e < 16; ++e) {
    int idx = tid + e * 256;
    T[idx >> 6][idx & 63] = X[(size_t)(j0 + (idx >> 6)) * DIM + d0 + (idx & 63)];
  }
  __syncthreads();
#pragma unroll
  for (int e = 0; e < 16; ++e) {
    int idx = tid + e * 256;
    int dd = idx >> 6, jj = idx & 63;
    int d = d0 + dd, j = j0 + jj;
    int lane = ((j >> 2) & 3) * 16 + (d & 15);
    int slot = (j & 3) | (((j >> 4) & 1) << 2);
    size_t off = ((size_t)(d >> 4) * 256 + (j >> 5)) * 512 + lane * 8 + slot;
    XhTf[off] = (f16)T[jj][dd];
  }
}

// ---------------------------------------------------------------------------
// FUSED projections: z=0 -> Q = (X Wq) * 1/sqrt(512); z=1 -> K = X Wk.
// R13 body: 128x128 tile, 4 waves, BK=32, 3-term split, XOR-swizzled LDS.
// ---------------------------------------------------------------------------
__global__ __launch_bounds__(256) void k_proj2z(
    const f16* __restrict__ Xh, const f16* __restrict__ Xl,
    const f16* __restrict__ Wthq, const f16* __restrict__ Wtlq,
    const f16* __restrict__ Wthk, const f16* __restrict__ Wtlk,
    f16* __restrict__ Qh, f16* __restrict__ Ql,
    f16* __restrict__ Kh, f16* __restrict__ Kl)
{
  __shared__ char sm[4 * 8192];
  const int tid  = threadIdx.x;
  const int lane = tid & 63;
  const int w    = tid >> 6;
  const int wm   = (w >> 1) * 64;
  const int wn   = (w & 1) * 64;
  const int row0g = blockIdx.x * 128;
  const int col0g = blockIdx.y * 128;
  const int z     = blockIdx.z;

  const f16* Wth = z ? Wthk : Wthq;
  const f16* Wtl = z ? Wtlk : Wtlq;
  f16* Oh = z ? Kh : Qh;
  f16* Ol = z ? Kl : Ql;
  const float scale = z ? 1.0f : 0.044194173824159216f;  // 1/sqrt(512)

  const int r1 = tid >> 2;
  const int o1 = (tid & 3) * 8;
  const int sw1 = (r1 * 64 + (tid & 3) * 16) ^ ((r1 & 7) << 4);
  const int sw2 = ((r1 + 64) * 64 + (tid & 3) * 16) ^ (((r1 + 64) & 7) << 4);
  const f16* pAh = Xh  + (size_t)(row0g + r1) * DIM + o1;
  const f16* pAl = Xl  + (size_t)(row0g + r1) * DIM + o1;
  const f16* pBh = Wth + (size_t)(col0g + r1) * DIM + o1;
  const f16* pBl = Wtl + (size_t)(col0g + r1) * DIM + o1;
  const int R64 = 64 * DIM;

  const int frow = lane & 15;
  const int fkb  = (lane >> 4) * 16;

  f32x4 acc[4][4] = {};

  for (int step = 0; step < 16; ++step) {
    const int d0 = step * 32;
    uint4 v0 = *(const uint4*)(pAh + d0);
    uint4 v1 = *(const uint4*)(pAh + R64 + d0);
    uint4 v2 = *(const uint4*)(pAl + d0);
    uint4 v3 = *(const uint4*)(pAl + R64 + d0);
    uint4 v4 = *(const uint4*)(pBh + d0);
    uint4 v5 = *(const uint4*)(pBh + R64 + d0);
    uint4 v6 = *(const uint4*)(pBl + d0);
    uint4 v7 = *(const uint4*)(pBl + R64 + d0);
    __syncthreads();
    *(uint4*)(sm +     0 + sw1) = v0;
    *(uint4*)(sm +     0 + sw2) = v1;
    *(uint4*)(sm +  8192 + sw1) = v2;
    *(uint4*)(sm +  8192 + sw2) = v3;
    *(uint4*)(sm + 16384 + sw1) = v4;
    *(uint4*)(sm + 16384 + sw2) = v5;
    *(uint4*)(sm + 24576 + sw1) = v6;
    *(uint4*)(sm + 24576 + sw2) = v7;
    __syncthreads();
    f16x8 aH[4], aL[4], bH[4], bL[4];
#pragma unroll
    for (int m = 0; m < 4; ++m) {
      int ra = wm + m * 16 + frow;
      int rb = wn + m * 16 + frow;
      int sa = (ra * 64 + fkb) ^ ((ra & 7) << 4);
      int sb = (rb * 64 + fkb) ^ ((rb & 7) << 4);
      aH[m] = *(const f16x8*)(sm +     0 + sa);
      aL[m] = *(const f16x8*)(sm +  8192 + sa);
      bH[m] = *(const f16x8*)(sm + 16384 + sb);
      bL[m] = *(const f16x8*)(sm + 24576 + sb);
    }
#pragma unroll
    for (int m = 0; m < 4; ++m)
#pragma unroll
      for (int n = 0; n < 4; ++n) {
        acc[m][n] = __builtin_amdgcn_mfma_f32_16x16x32_f16(aH[m], bH[n], acc[m][n], 0, 0, 0);
        acc[m][n] = __builtin_amdgcn_mfma_f32_16x16x32_f16(aH[m], bL[n], acc[m][n], 0, 0, 0);
        acc[m][n] = __builtin_amdgcn_mfma_f32_16x16x32_f16(aL[m], bH[n], acc[m][n], 0, 0, 0);
      }
  }

  const int row0 = row0g + wm;
  const int col0 = col0g + wn;
#pragma unroll
  for (int m = 0; m < 4; ++m)
#pragma unroll
    for (int n = 0; n < 4; ++n) {
      int row = row0 + m * 16 + (lane >> 4) * 4;
      int col = col0 + n * 16 + frow;
#pragma unroll
      for (int r = 0; r < 4; ++r) {
        float c = acc[m][n][r] * scale;
        f16 h = (f16)c;
        Oh[(size_t)(row + r) * DIM + col] = h;
        Ol[(size_t)(row + r) * DIM + col] = (f16)(c - (float)h);
      }
    }
}

// ---------------------------------------------------------------------------
// S^T = K Q^T via split-f16 MFMA (R13 exact). Epilogue writes C-native
// 16x16 f32 frags (coalesced) AND per-wave column maxes to mrowp[slot][q].
// ---------------------------------------------------------------------------
__global__ __launch_bounds__(256) void k_qkt_t(
    const f16* __restrict__ Kh, const f16* __restrict__ Kl,
    const f16* __restrict__ Qh, const f16* __restrict__ Ql,
    float* __restrict__ ST, float* __restrict__ mrowp, int q0)
{
  __shared__ char sm[4 * 8192];
  const int tid  = threadIdx.x;
  const int lane = tid & 63;
  const int w    = tid >> 6;
  const int wm   = (w >> 1) * 64;          // j offset in tile
  const int wn   = (w & 1) * 64;           // q offset in tile
  const int jrow0 = blockIdx.x * 128;
  const int qrow0 = q0 + blockIdx.y * 128;

  const int r1 = tid >> 2;
  const int o1 = (tid & 3) * 8;
  const int sw1 = (r1 * 64 + (tid & 3) * 16) ^ ((r1 & 7) << 4);
  const int sw2 = ((r1 + 64) * 64 + (tid & 3) * 16) ^ (((r1 + 64) & 7) << 4);
  const f16* pAh = Kh + (size_t)(jrow0 + r1) * DIM + o1;
  const f16* pAl = Kl + (size_t)(jrow0 + r1) * DIM + o1;
  const f16* pBh = Qh + (size_t)(qrow0 + r1) * DIM + o1;
  const f16* pBl = Ql + (size_t)(qrow0 + r1) * DIM + o1;
  const int R64 = 64 * DIM;

  const int frow = lane & 15;
  const int fkb  = (lane >> 4) * 16;

  f32x4 acc[4][4] = {};

  for (int step = 0; step < 16; ++step) {
    const int d0 = step * 32;
    uint4 v0 = *(const uint4*)(pAh + d0);
    uint4 v1 = *(const uint4*)(pAh + R64 + d0);
    uint4 v2 = *(const uint4*)(pAl + d0);
    uint4 v3 = *(const uint4*)(pAl + R64 + d0);
    uint4 v4 = *(const uint4*)(pBh + d0);
    uint4 v5 = *(const uint4*)(pBh + R64 + d0);
    uint4 v6 = *(const uint4*)(pBl + d0);
    uint4 v7 = *(const uint4*)(pBl + R64 + d0);
    __syncthreads();
    *(uint4*)(sm +     0 + sw1) = v0;
    *(uint4*)(sm +     0 + sw2) = v1;
    *(uint4*)(sm +  8192 + sw1) = v2;
    *(uint4*)(sm +  8192 + sw2) = v3;
    *(uint4*)(sm + 16384 + sw1) = v4;
    *(uint4*)(sm + 16384 + sw2) = v5;
    *(uint4*)(sm + 24576 + sw1) = v6;
    *(uint4*)(sm + 24576 + sw2) = v7;
    __syncthreads();
    f16x8 aH[4], aL[4], bH[4], bL[4];
#pragma unroll
    for (int m = 0; m < 4; ++m) {
      int ra = wm + m * 16 + frow;
      int rb = wn + m * 16 + frow;
      int sa = (ra * 64 + fkb) ^ ((ra & 7) << 4);
      int sb = (rb * 64 + fkb) ^ ((rb & 7) << 4);
      aH[m] = *(const f16x8*)(sm +     0 + sa);
      aL[m] = *(const f16x8*)(sm +  8192 + sa);
      bH[m] = *(const f16x8*)(sm + 16384 + sb);
      bL[m] = *(const f16x8*)(sm + 24576 + sb);
    }
#pragma unroll
    for (int m = 0; m < 4; ++m)
#pragma unroll
      for (int n = 0; n < 4; ++n) {
        acc[m][n] = __builtin_amdgcn_mfma_f32_16x16x32_f16(aH[m], bH[n], acc[m][n], 0, 0, 0);
        acc[m][n] = __builtin_amdgcn_mfma_f32_16x16x32_f16(aH[m], bL[n], acc[m][n], 0, 0, 0);
        acc[m][n] = __builtin_amdgcn_mfma_f32_16x16x32_f16(aL[m], bH[n], acc[m][n], 0, 0, 0);
      }
  }

  const int jt0 = (blockIdx.x * 128 + wm) >> 4;
  const int qt0 = ((blockIdx.y * 128) + wn) >> 4;   // chunk-local
#pragma unroll
  for (int m = 0; m < 4; ++m)
#pragma unroll
    for (int n = 0; n < 4; ++n) {
      float* dst = ST + ((size_t)(qt0 + n) * 512 + (jt0 + m)) * 256 + lane * 4;
      *(f32x4*)dst = acc[m][n];
    }

  const int slot = blockIdx.x * 2 + (w >> 1);
#pragma unroll
  for (int n = 0; n < 4; ++n) {
    float cm = -3.0e38f;
#pragma unroll
    for (int m = 0; m < 4; ++m)
#pragma unroll
      for (int r = 0; r < 4; ++r) cm = fmaxf(cm, acc[m][n][r]);
    cm = fmaxf(cm, __shfl_xor(cm, 16));
    cm = fmaxf(cm, __shfl_xor(cm, 32));
    if (lane < 16)
      mrowp[(size_t)slot * NSEQ + qrow0 + wn + n * 16 + lane] = cm;
  }
}

// ---------------------------------------------------------------------------
// Fused rowmax + exp + PV v2: Opart^T = XhTf * exp(S^T - m)^T.
// Wave = 64 d x 32 q; block = 4 waves = 256 d x 32 q. Grid = (CQ/32) *
// 2(d-half) * JSL. Prologue computes the 32 row-maxes from mrowp (smax2
// fused). Main loop: DEPTH-2 ST register prefetch (4 named buffer sets,
// hand-unrolled x4). exp via fma+exp2. No LDS, no barriers.
// ---------------------------------------------------------------------------
__global__ __launch_bounds__(256, 4) void k_pvx4(
    const f16* __restrict__ XhTf, const float* __restrict__ ST,
    const float* __restrict__ mrowp, float* __restrict__ obase, size_t zstride,
    float* __restrict__ lpart, int q0, int jrange, int gsh)
{
  const int tid  = threadIdx.x;
  const int lane = tid & 63;
  const int w    = tid >> 6;

  const int bid = blockIdx.x;
  const int sub = bid & ((1 << gsh) - 1);
  const int qg  = bid >> gsh;
  const int dh  = sub & 1;
  const int zp  = sub >> 1;
  const int qg0 = q0 + qg * 32;

  // ---- fused row-max: max over 128 slots for q = qg0 + (lane&31) ----
  const float LOG2E = 1.4426950408889634f;
  float mx = -3.0e38f;
  {
    const float* mp = mrowp + qg0 + (lane & 31) + (size_t)((lane >> 5) * 64) * NSEQ;
#pragma unroll 8
    for (int s2 = 0; s2 < 64; ++s2)
      mx = fmaxf(mx, mp[(size_t)s2 * NSEQ]);
    mx = fmaxf(mx, __shfl_xor(mx, 32));
  }
  const float nm0 = -__shfl(mx, lane & 15) * LOG2E;
  const float nm1 = -__shfl(mx, 16 + (lane & 15)) * LOG2E;

  const f16* pa = XhTf + ((size_t)(dh * 16 + w * 4) * 256 + (zp * jrange >> 5)) * 512
                + lane * 8;
  const float* pb0 = ST + ((size_t)(qg * 2) * 512 + (zp * jrange >> 4)) * 256 + lane * 4;
  const float* pb1 = pb0 + (size_t)512 * 256;

  f32x4 acc[4][2] = {};
  float lsum0 = 0.f, lsum1 = 0.f;
  const int nsteps = jrange / 32;

#define LDB(P, I) (*(const f32x4*)((P) + (size_t)(I) * 256))
#define LDA(M, S) (*(const f16x8*)(pa + ((size_t)(M) * 256 + (S)) * 512))

  // buffer sets: a=step s, b=step s+1 (preloaded); c,d filled in-loop.
  f32x4 aS0 = LDB(pb0, 0), aS1 = LDB(pb0, 1), aS2 = LDB(pb1, 0), aS3 = LDB(pb1, 1);
  f32x4 bS0 = LDB(pb0, 2), bS1 = LDB(pb0, 3), bS2 = LDB(pb1, 2), bS3 = LDB(pb1, 3);
  f32x4 cS0, cS1, cS2, cS3, dS0, dS1, dS2, dS3;

#define PV_STEP(C0, C1, C2, C3, N0, N1, N2, N3, S)                            \
  {                                                                           \
    const int sn_ = ((S) + 2 < nsteps) ? (S) + 2 : (nsteps - 1);              \
    N0 = LDB(pb0, 2 * sn_);     N1 = LDB(pb0, 2 * sn_ + 1);                   \
    N2 = LDB(pb1, 2 * sn_);     N3 = LDB(pb1, 2 * sn_ + 1);                   \
    f16x8 b0, b1;                                                             \
    _Pragma("unroll")                                                         \
    for (int i = 0; i < 4; ++i) {                                             \
      float p0 = exp2f(fmaf(C0[i], LOG2E, nm0)); lsum0 += p0; b0[i] = (f16)p0; \
      float p1 = exp2f(fmaf(C1[i], LOG2E, nm0)); lsum0 += p1; b0[4 + i] = (f16)p1; \
      float p2 = exp2f(fmaf(C2[i], LOG2E, nm1)); lsum1 += p2; b1[i] = (f16)p2; \
      float p3 = exp2f(fmaf(C3[i], LOG2E, nm1)); lsum1 += p3; b1[4 + i] = (f16)p3; \
    }                                                                         \
    _Pragma("unroll")                                                         \
    for (int m2 = 0; m2 < 4; ++m2) {                                          \
      f16x8 a = LDA(m2, (S));                                                 \
      acc[m2][0] = __builtin_amdgcn_mfma_f32_16x16x32_f16(a, b0, acc[m2][0], 0, 0, 0); \
      acc[m2][1] = __builtin_amdgcn_mfma_f32_16x16x32_f16(a, b1, acc[m2][1], 0, 0, 0); \
    }                                                                         \
  }

  for (int s = 0; s < nsteps; s += 4) {
    PV_STEP(aS0, aS1, aS2, aS3, cS0, cS1, cS2, cS3, s);
    PV_STEP(bS0, bS1, bS2, bS3, dS0, dS1, dS2, dS3, s + 1);
    PV_STEP(cS0, cS1, cS2, cS3, aS0, aS1, aS2, aS3, s + 2);
    PV_STEP(dS0, dS1, dS2, dS3, bS0, bS1, bS2, bS3, s + 3);
  }
#undef PV_STEP
#undef LDA
#undef LDB

  lsum0 += __shfl_xor(lsum0, 16);
  lsum0 += __shfl_xor(lsum0, 32);
  lsum1 += __shfl_xor(lsum1, 16);
  lsum1 += __shfl_xor(lsum1, 32);
  if (dh == 0 && w == 0 && lane < 16) {
    lpart[(size_t)zp * NSEQ + qg0 + lane]      = lsum0;
    lpart[(size_t)zp * NSEQ + qg0 + 16 + lane] = lsum1;
  }

#pragma unroll
  for (int n2 = 0; n2 < 2; ++n2) {
    const int qg2 = qg0 + n2 * 16 + (lane & 15);
    float* op = obase + (size_t)zp * zstride + (size_t)qg2 * DIM;
#pragma unroll
    for (int m2 = 0; m2 < 4; ++m2)
      *(f32x4*)(op + dh * 256 + w * 64 + m2 * 16 + (lane >> 4) * 4) = acc[m2][n2];
  }
}

// ---------------------------------------------------------------------------
// Out[q][d] = (sum_zp Opart[zp][q][d]) / (sum_zp lpart[zp][q]).
// Works in place when obase==Out (JSL==1, zstride==0).
// ---------------------------------------------------------------------------
__global__ __launch_bounds__(256) void k_reduce2(
    const float* __restrict__ obase, size_t zstride, int ZP,
    const float* __restrict__ lpart, float* __restrict__ Out)
{
  const int idx = blockIdx.x * 256 + threadIdx.x;
  const int q = idx >> 7;
  const int d4 = idx & 127;
  const float* p = obase + (size_t)q * DIM + (size_t)d4 * 4;
  f32x4 s = *(const f32x4*)p;
  float l = lpart[q];
  for (int zz = 1; zz < ZP; ++zz) {
    s += *(const f32x4*)(p + (size_t)zz * zstride);
    l += lpart[(size_t)zz * NSEQ + q];
  }
  s *= (1.0f / l);
  *(f32x4*)(Out + (size_t)q * DIM + d4 * 4) = s;
}

// ---------------------------------------------------------------------------
extern "C" void kernel_launch(void* const* d_in, const int* in_sizes, int n_in,
                              void* d_out, int out_size, void* d_ws, size_t ws_size,
                              hipStream_t stream) {
  const float* Wq = (const float*)d_in[0];
  const float* Wk = (const float*)d_in[1];
  const float* X  = (const float*)d_in[2];
  float* Out = (float*)d_out;

  char* w = (char*)d_ws;
  const size_t SPLIT = (size_t)NSEQ * DIM * 2;           // 8 MB
  const size_t XFB   = (size_t)NSEQ * DIM * 2;           // 8 MB frag XhTf
  const size_t WTB   = (size_t)DIM * DIM * 2;            // 512 KB
  const size_t MRPB  = (size_t)128 * NSEQ * 4;           // 4 MB mrowp
  f16* Qh   = (f16*)(w);
  f16* Ql   = (f16*)(w + SPLIT);
  f16* Kh   = (f16*)(w + 2 * SPLIT);
  f16* Kl   = (f16*)(w + 3 * SPLIT);
  f16* XhTf = (f16*)(w + 4 * SPLIT);
  f16* Xh   = (f16*)(w + 4 * SPLIT + XFB);
  f16* Xl   = (f16*)(w + 5 * SPLIT + XFB);
  f16* Wthq = (f16*)(w + 6 * SPLIT + XFB);
  f16* Wtlq = (f16*)(w + 6 * SPLIT + XFB + WTB);
  f16* Wthk = (f16*)(w + 6 * SPLIT + XFB + 2 * WTB);
  f16* Wtlk = (f16*)(w + 6 * SPLIT + XFB + 3 * WTB);
  float* lpart = (float*)(w + 6 * SPLIT + XFB + 4 * WTB + 32768);      // 256 KB
  float* mrowp = (float*)(w + 6 * SPLIT + XFB + 4 * WTB + 327680);     // 4 MB
  const size_t used_base = 6 * SPLIT + XFB + 4 * WTB + 327680 + MRPB;
  char* rest = w + used_base;
  const size_t OPART1 = (size_t)NSEQ * DIM * 4;          // 16 MB per partial
  const size_t avail = (ws_size > used_base) ? ws_size - used_base : 0;

  // pick (CQ, JSL): best measured config {4096,4} first.
  const int cands[8][2] = {{4096,4},{4096,2},{2048,4},{2048,2},
                           {1024,2},{1024,1},{512,1},{256,1}};
  int CQ = 256, JSL = 1;
  for (int c = 0; c < 8; ++c) {
    size_t need = (size_t)cands[c][0] * NSEQ * 4 +
                  (cands[c][1] > 1 ? (size_t)cands[c][1] * OPART1 : 0);
    if (need <= avail) { CQ = cands[c][0]; JSL = cands[c][1]; break; }
  }
  const int gsh = (JSL == 4) ? 3 : (JSL == 2) ? 2 : 1;

  float* ST = (float*)rest;
  float* obase; size_t zstride;
  if (JSL > 1) { obase = (float*)(rest + (size_t)CQ * NSEQ * 4); zstride = (size_t)NSEQ * DIM; }
  else         { obase = Out; zstride = 0; }

  k_splitx<<<NSEQ * DIM / (256 * 4), 256, 0, stream>>>(X, Xh, Xl);
  k_xt2<<<dim3(NSEQ / 64, DIM / 64), 256, 0, stream>>>(X, XhTf);
  k_splitwt2<<<dim3(8, 8, 2), 256, 0, stream>>>(Wq, Wk, Wthq, Wtlq, Wthk, Wtlk);
  k_proj2z<<<dim3(NSEQ / 128, DIM / 128, 2), 256, 0, stream>>>(
      Xh, Xl, Wthq, Wtlq, Wthk, Wtlk, Qh, Ql, Kh, Kl);

  for (int q0 = 0; q0 < NSEQ; q0 += CQ) {
    k_qkt_t<<<dim3(NSEQ / 128, CQ / 128), 256, 0, stream>>>(Kh, Kl, Qh, Ql, ST, mrowp, q0);
    k_pvx4<<<dim3((CQ / 32) << gsh), 256, 0, stream>>>(XhTf, ST, mrowp, obase, zstride,
                                                       lpart, q0, NSEQ / JSL, gsh);
  }
  k_reduce2<<<NSEQ * (DIM / 4) / 256, 256, 0, stream>>>(obase, zstride, JSL, lpart, Out);
}

// Round 20
// 530.744 us; speedup vs baseline: 1.0341x; 1.0341x over previous
//
#include <hip/hip_runtime.h>
#include <hip/hip_fp16.h>

#define NSEQ 8192
#define DIM  512

typedef _Float16 f16;
typedef _Float16 f16x8 __attribute__((ext_vector_type(8)));
typedef _Float16 f16x4 __attribute__((ext_vector_type(4)));
typedef float    f32x4 __attribute__((ext_vector_type(4)));

// S^T fragment layout (16x16 f32, C-native): frag(qt, jt) at
//   ST + ((size_t)qt*512 + jt)*256 ; lane l's 4 values at +l*4
// XhTf layout (k-permuted): element (d, j): frag = (d>>4)*256 + (j>>5);
//   lane = ((j>>2)&3)*16 + (d&15); slot e = (j&3)|(((j>>4)&1)<<2).
// qkt/proj staging: R13 variant (fastest of 4 measured): XOR-swizzled
//   row-major LDS, reg-staged, loads at top of step.
// pvx4: R18 body (depth-1 reg dbuf — deeper prefetch is compiler-defeated);
//   NEW decode: dh moved to bid>>gsh bit0 so the dh=0/1 pair (which reads
//   identical ST bytes) lands on the SAME XCD -> 2nd read L2-hits.

// ---------------------------------------------------------------------------
// X (fp32) -> Xh + Xl (f16 hi/lo split), row-major.
// ---------------------------------------------------------------------------
__global__ __launch_bounds__(256) void k_splitx(const float* __restrict__ X,
                                                f16* __restrict__ Xh,
                                                f16* __restrict__ Xl)
{
  const size_t idx = (size_t)blockIdx.x * 256 + threadIdx.x;
  f32x4 v = *(const f32x4*)(X + idx * 4);
  f16x4 h, l;
#pragma unroll
  for (int i = 0; i < 4; ++i) {
    h[i] = (f16)v[i];
    l[i] = (f16)(v[i] - (float)h[i]);
  }
  *(f16x4*)(Xh + idx * 4) = h;
  *(f16x4*)(Xl + idx * 4) = l;
}

// ---------------------------------------------------------------------------
// Both W's (512x512 fp32) -> Wt^T split, z selects Wq/Wk.
// ---------------------------------------------------------------------------
__global__ __launch_bounds__(256) void k_splitwt2(
    const float* __restrict__ Wq, const float* __restrict__ Wk,
    f16* __restrict__ Thq, f16* __restrict__ Tlq,
    f16* __restrict__ Thk, f16* __restrict__ Tlk)
{
  __shared__ float T[64][65];
  const int tid = threadIdx.x;
  const int k0 = blockIdx.x * 64;
  const int c0 = blockIdx.y * 64;
  const float* W = blockIdx.z ? Wk : Wq;
  f16* Th = blockIdx.z ? Thk : Thq;
  f16* Tl = blockIdx.z ? Tlk : Tlq;
#pragma unroll
  for (int e = 0; e < 16; ++e) {
    int idx = tid + e * 256;
    T[idx >> 6][idx & 63] = W[(size_t)(k0 + (idx >> 6)) * DIM + c0 + (idx & 63)];
  }
  __syncthreads();
#pragma unroll
  for (int e = 0; e < 16; ++e) {
    int idx = tid + e * 256;
    int cc = idx >> 6, kk = idx & 63;
    float v = T[kk][cc];
    f16 h = (f16)v;
    Th[(size_t)(c0 + cc) * DIM + k0 + kk] = h;
    Tl[(size_t)(c0 + cc) * DIM + k0 + kk] = (f16)(v - (float)h);
  }
}

// ---------------------------------------------------------------------------
// X -> XhTf: k-permuted frag-tiled V^T (rows = d, k-cols = j).
// ---------------------------------------------------------------------------
__global__ __launch_bounds__(256) void k_xt2(const float* __restrict__ X,
                                             f16* __restrict__ XhTf)
{
  __shared__ float T[64][65];
  const int tid = threadIdx.x;
  const int j0 = blockIdx.x * 64;
  const int d0 = blockIdx.y * 64;
#pragma unroll
  for (int e = 0; e < 16; ++e) {
    int idx = tid + e * 256;
    T[idx >> 6][idx & 63] = X[(size_t)(j0 + (idx >> 6)) * DIM + d0 + (idx & 63)];
  }
  __syncthreads();
#pragma unroll
  for (int e = 0; e < 16; ++e) {
    int idx = tid + e * 256;
    int dd = idx >> 6, jj = idx & 63;
    int d = d0 + dd, j = j0 + jj;
    int lane = ((j >> 2) & 3) * 16 + (d & 15);
    int slot = (j & 3) | (((j >> 4) & 1) << 2);
    size_t off = ((size_t)(d >> 4) * 256 + (j >> 5)) * 512 + lane * 8 + slot;
    XhTf[off] = (f16)T[jj][dd];
  }
}

// ---------------------------------------------------------------------------
// FUSED projections: z=0 -> Q = (X Wq) * 1/sqrt(512); z=1 -> K = X Wk.
// R13 body: 128x128 tile, 4 waves, BK=32, 3-term split, XOR-swizzled LDS.
// ---------------------------------------------------------------------------
__global__ __launch_bounds__(256) void k_proj2z(
    const f16* __restrict__ Xh, const f16* __restrict__ Xl,
    const f16* __restrict__ Wthq, const f16* __restrict__ Wtlq,
    const f16* __restrict__ Wthk, const f16* __restrict__ Wtlk,
    f16* __restrict__ Qh, f16* __restrict__ Ql,
    f16* __restrict__ Kh, f16* __restrict__ Kl)
{
  __shared__ char sm[4 * 8192];
  const int tid  = threadIdx.x;
  const int lane = tid & 63;
  const int w    = tid >> 6;
  const int wm   = (w >> 1) * 64;
  const int wn   = (w & 1) * 64;
  const int row0g = blockIdx.x * 128;
  const int col0g = blockIdx.y * 128;
  const int z     = blockIdx.z;

  const f16* Wth = z ? Wthk : Wthq;
  const f16* Wtl = z ? Wtlk : Wtlq;
  f16* Oh = z ? Kh : Qh;
  f16* Ol = z ? Kl : Ql;
  const float scale = z ? 1.0f : 0.044194173824159216f;  // 1/sqrt(512)

  const int r1 = tid >> 2;
  const int o1 = (tid & 3) * 8;
  const int sw1 = (r1 * 64 + (tid & 3) * 16) ^ ((r1 & 7) << 4);
  const int sw2 = ((r1 + 64) * 64 + (tid & 3) * 16) ^ (((r1 + 64) & 7) << 4);
  const f16* pAh = Xh  + (size_t)(row0g + r1) * DIM + o1;
  const f16* pAl = Xl  + (size_t)(row0g + r1) * DIM + o1;
  const f16* pBh = Wth + (size_t)(col0g + r1) * DIM + o1;
  const f16* pBl = Wtl + (size_t)(col0g + r1) * DIM + o1;
  const int R64 = 64 * DIM;

  const int frow = lane & 15;
  const int fkb  = (lane >> 4) * 16;

  f32x4 acc[4][4] = {};

  for (int step = 0; step < 16; ++step) {
    const int d0 = step * 32;
    uint4 v0 = *(const uint4*)(pAh + d0);
    uint4 v1 = *(const uint4*)(pAh + R64 + d0);
    uint4 v2 = *(const uint4*)(pAl + d0);
    uint4 v3 = *(const uint4*)(pAl + R64 + d0);
    uint4 v4 = *(const uint4*)(pBh + d0);
    uint4 v5 = *(const uint4*)(pBh + R64 + d0);
    uint4 v6 = *(const uint4*)(pBl + d0);
    uint4 v7 = *(const uint4*)(pBl + R64 + d0);
    __syncthreads();
    *(uint4*)(sm +     0 + sw1) = v0;
    *(uint4*)(sm +     0 + sw2) = v1;
    *(uint4*)(sm +  8192 + sw1) = v2;
    *(uint4*)(sm +  8192 + sw2) = v3;
    *(uint4*)(sm + 16384 + sw1) = v4;
    *(uint4*)(sm + 16384 + sw2) = v5;
    *(uint4*)(sm + 24576 + sw1) = v6;
    *(uint4*)(sm + 24576 + sw2) = v7;
    __syncthreads();
    f16x8 aH[4], aL[4], bH[4], bL[4];
#pragma unroll
    for (int m = 0; m < 4; ++m) {
      int ra = wm + m * 16 + frow;
      int rb = wn + m * 16 + frow;
      int sa = (ra * 64 + fkb) ^ ((ra & 7) << 4);
      int sb = (rb * 64 + fkb) ^ ((rb & 7) << 4);
      aH[m] = *(const f16x8*)(sm +     0 + sa);
      aL[m] = *(const f16x8*)(sm +  8192 + sa);
      bH[m] = *(const f16x8*)(sm + 16384 + sb);
      bL[m] = *(const f16x8*)(sm + 24576 + sb);
    }
#pragma unroll
    for (int m = 0; m < 4; ++m)
#pragma unroll
      for (int n = 0; n < 4; ++n) {
        acc[m][n] = __builtin_amdgcn_mfma_f32_16x16x32_f16(aH[m], bH[n], acc[m][n], 0, 0, 0);
        acc[m][n] = __builtin_amdgcn_mfma_f32_16x16x32_f16(aH[m], bL[n], acc[m][n], 0, 0, 0);
        acc[m][n] = __builtin_amdgcn_mfma_f32_16x16x32_f16(aL[m], bH[n], acc[m][n], 0, 0, 0);
      }
  }

  const int row0 = row0g + wm;
  const int col0 = col0g + wn;
#pragma unroll
  for (int m = 0; m < 4; ++m)
#pragma unroll
    for (int n = 0; n < 4; ++n) {
      int row = row0 + m * 16 + (lane >> 4) * 4;
      int col = col0 + n * 16 + frow;
#pragma unroll
      for (int r = 0; r < 4; ++r) {
        float c = acc[m][n][r] * scale;
        f16 h = (f16)c;
        Oh[(size_t)(row + r) * DIM + col] = h;
        Ol[(size_t)(row + r) * DIM + col] = (f16)(c - (float)h);
      }
    }
}

// ---------------------------------------------------------------------------
// S^T = K Q^T via split-f16 MFMA (R13 exact). Epilogue writes C-native
// 16x16 f32 frags (coalesced) AND per-wave column maxes to mrowp[slot][q].
// ---------------------------------------------------------------------------
__global__ __launch_bounds__(256) void k_qkt_t(
    const f16* __restrict__ Kh, const f16* __restrict__ Kl,
    const f16* __restrict__ Qh, const f16* __restrict__ Ql,
    float* __restrict__ ST, float* __restrict__ mrowp, int q0)
{
  __shared__ char sm[4 * 8192];
  const int tid  = threadIdx.x;
  const int lane = tid & 63;
  const int w    = tid >> 6;
  const int wm   = (w >> 1) * 64;          // j offset in tile
  const int wn   = (w & 1) * 64;           // q offset in tile
  const int jrow0 = blockIdx.x * 128;
  const int qrow0 = q0 + blockIdx.y * 128;

  const int r1 = tid >> 2;
  const int o1 = (tid & 3) * 8;
  const int sw1 = (r1 * 64 + (tid & 3) * 16) ^ ((r1 & 7) << 4);
  const int sw2 = ((r1 + 64) * 64 + (tid & 3) * 16) ^ (((r1 + 64) & 7) << 4);
  const f16* pAh = Kh + (size_t)(jrow0 + r1) * DIM + o1;
  const f16* pAl = Kl + (size_t)(jrow0 + r1) * DIM + o1;
  const f16* pBh = Qh + (size_t)(qrow0 + r1) * DIM + o1;
  const f16* pBl = Ql + (size_t)(qrow0 + r1) * DIM + o1;
  const int R64 = 64 * DIM;

  const int frow = lane & 15;
  const int fkb  = (lane >> 4) * 16;

  f32x4 acc[4][4] = {};

  for (int step = 0; step < 16; ++step) {
    const int d0 = step * 32;
    uint4 v0 = *(const uint4*)(pAh + d0);
    uint4 v1 = *(const uint4*)(pAh + R64 + d0);
    uint4 v2 = *(const uint4*)(pAl + d0);
    uint4 v3 = *(const uint4*)(pAl + R64 + d0);
    uint4 v4 = *(const uint4*)(pBh + d0);
    uint4 v5 = *(const uint4*)(pBh + R64 + d0);
    uint4 v6 = *(const uint4*)(pBl + d0);
    uint4 v7 = *(const uint4*)(pBl + R64 + d0);
    __syncthreads();
    *(uint4*)(sm +     0 + sw1) = v0;
    *(uint4*)(sm +     0 + sw2) = v1;
    *(uint4*)(sm +  8192 + sw1) = v2;
    *(uint4*)(sm +  8192 + sw2) = v3;
    *(uint4*)(sm + 16384 + sw1) = v4;
    *(uint4*)(sm + 16384 + sw2) = v5;
    *(uint4*)(sm + 24576 + sw1) = v6;
    *(uint4*)(sm + 24576 + sw2) = v7;
    __syncthreads();
    f16x8 aH[4], aL[4], bH[4], bL[4];
#pragma unroll
    for (int m = 0; m < 4; ++m) {
      int ra = wm + m * 16 + frow;
      int rb = wn + m * 16 + frow;
      int sa = (ra * 64 + fkb) ^ ((ra & 7) << 4);
      int sb = (rb * 64 + fkb) ^ ((rb & 7) << 4);
      aH[m] = *(const f16x8*)(sm +     0 + sa);
      aL[m] = *(const f16x8*)(sm +  8192 + sa);
      bH[m] = *(const f16x8*)(sm + 16384 + sb);
      bL[m] = *(const f16x8*)(sm + 24576 + sb);
    }
#pragma unroll
    for (int m = 0; m < 4; ++m)
#pragma unroll
      for (int n = 0; n < 4; ++n) {
        acc[m][n] = __builtin_amdgcn_mfma_f32_16x16x32_f16(aH[m], bH[n], acc[m][n], 0, 0, 0);
        acc[m][n] = __builtin_amdgcn_mfma_f32_16x16x32_f16(aH[m], bL[n], acc[m][n], 0, 0, 0);
        acc[m][n] = __builtin_amdgcn_mfma_f32_16x16x32_f16(aL[m], bH[n], acc[m][n], 0, 0, 0);
      }
  }

  const int jt0 = (blockIdx.x * 128 + wm) >> 4;
  const int qt0 = ((blockIdx.y * 128) + wn) >> 4;   // chunk-local
#pragma unroll
  for (int m = 0; m < 4; ++m)
#pragma unroll
    for (int n = 0; n < 4; ++n) {
      float* dst = ST + ((size_t)(qt0 + n) * 512 + (jt0 + m)) * 256 + lane * 4;
      *(f32x4*)dst = acc[m][n];
    }

  const int slot = blockIdx.x * 2 + (w >> 1);
#pragma unroll
  for (int n = 0; n < 4; ++n) {
    float cm = -3.0e38f;
#pragma unroll
    for (int m = 0; m < 4; ++m)
#pragma unroll
      for (int r = 0; r < 4; ++r) cm = fmaxf(cm, acc[m][n][r]);
    cm = fmaxf(cm, __shfl_xor(cm, 16));
    cm = fmaxf(cm, __shfl_xor(cm, 32));
    if (lane < 16)
      mrowp[(size_t)slot * NSEQ + qrow0 + wn + n * 16 + lane] = cm;
  }
}

// ---------------------------------------------------------------------------
// Reduce 128 per-slot column maxes -> mrow[q], for q in [q0, q0+CQ).
// ---------------------------------------------------------------------------
__global__ __launch_bounds__(256) void k_smax2(
    const float* __restrict__ mrowp, float* __restrict__ mrow, int q0)
{
  const int q = q0 + blockIdx.x * 256 + threadIdx.x;
  float mx = -3.0e38f;
#pragma unroll 8
  for (int s = 0; s < 128; ++s)
    mx = fmaxf(mx, mrowp[(size_t)s * NSEQ + q]);
  mrow[q] = mx;
}

// ---------------------------------------------------------------------------
// Fused exp + PV (R18 body): wave = 64 d x 32 q; block = 4 waves = 256 d x
// 32 q. Grid = (CQ/32) * 2(d-half) * JSL. NEW decode: low gsh bits =
// (zp, qpar); dh = (bid>>gsh)&1 -> the dh pair (identical ST reads) is 8
// apart in bid = SAME XCD = second read L2-hits. ST register-dbuf depth 1;
// exp via fma+exp2.
// ---------------------------------------------------------------------------
__global__ __launch_bounds__(256, 4) void k_pvx4(
    const f16* __restrict__ XhTf, const float* __restrict__ ST,
    const float* __restrict__ mrow, float* __restrict__ obase, size_t zstride,
    float* __restrict__ lpart, int q0, int jrange, int gsh)
{
  const int tid  = threadIdx.x;
  const int lane = tid & 63;
  const int w    = tid >> 6;

  const int bid  = blockIdx.x;
  const int low  = bid & ((1 << gsh) - 1);
  const int zp   = low >> 1;
  const int qpar = low & 1;
  const int g    = bid >> gsh;
  const int dh   = g & 1;
  const int qg   = (g >> 1) * 2 + qpar;
  const int qg0  = q0 + qg * 32;

  const float LOG2E = 1.4426950408889634f;
  const float nm0 = -mrow[qg0 + (lane & 15)] * LOG2E;
  const float nm1 = -mrow[qg0 + 16 + (lane & 15)] * LOG2E;

  const f16* pa = XhTf + ((size_t)(dh * 16 + w * 4) * 256 + (zp * jrange >> 5)) * 512
                + lane * 8;
  const float* pb0 = ST + ((size_t)(qg * 2) * 512 + (zp * jrange >> 4)) * 256 + lane * 4;
  const float* pb1 = pb0 + (size_t)512 * 256;

  f32x4 acc[4][2] = {};
  float lsum0 = 0.f, lsum1 = 0.f;
  const int nsteps = jrange / 32;

#define LDB(P, I) (*(const f32x4*)((P) + (size_t)(I) * 256))
#define LDA(M, S) (*(const f16x8*)(pa + ((size_t)(M) * 256 + (S)) * 512))

  f32x4 sa0 = LDB(pb0, 0), sa1 = LDB(pb0, 1);
  f32x4 sb0 = LDB(pb1, 0), sb1 = LDB(pb1, 1);

  for (int s = 0; s < nsteps; ++s) {
    const int sn = (s + 1 < nsteps) ? s + 1 : s;
    f32x4 ta0 = LDB(pb0, 2 * sn), ta1 = LDB(pb0, 2 * sn + 1);
    f32x4 tb0 = LDB(pb1, 2 * sn), tb1 = LDB(pb1, 2 * sn + 1);
    f16x8 b0, b1;
#pragma unroll
    for (int i = 0; i < 4; ++i) {
      float p0 = exp2f(fmaf(sa0[i], LOG2E, nm0)); lsum0 += p0; b0[i] = (f16)p0;
      float p1 = exp2f(fmaf(sa1[i], LOG2E, nm0)); lsum0 += p1; b0[4 + i] = (f16)p1;
      float p2 = exp2f(fmaf(sb0[i], LOG2E, nm1)); lsum1 += p2; b1[i] = (f16)p2;
      float p3 = exp2f(fmaf(sb1[i], LOG2E, nm1)); lsum1 += p3; b1[4 + i] = (f16)p3;
    }
#pragma unroll
    for (int m2 = 0; m2 < 4; ++m2) {
      f16x8 a = LDA(m2, s);
      acc[m2][0] = __builtin_amdgcn_mfma_f32_16x16x32_f16(a, b0, acc[m2][0], 0, 0, 0);
      acc[m2][1] = __builtin_amdgcn_mfma_f32_16x16x32_f16(a, b1, acc[m2][1], 0, 0, 0);
    }
    sa0 = ta0; sa1 = ta1; sb0 = tb0; sb1 = tb1;
  }
#undef LDA
#undef LDB

  lsum0 += __shfl_xor(lsum0, 16);
  lsum0 += __shfl_xor(lsum0, 32);
  lsum1 += __shfl_xor(lsum1, 16);
  lsum1 += __shfl_xor(lsum1, 32);
  if (dh == 0 && w == 0 && lane < 16) {
    lpart[(size_t)zp * NSEQ + qg0 + lane]      = lsum0;
    lpart[(size_t)zp * NSEQ + qg0 + 16 + lane] = lsum1;
  }

#pragma unroll
  for (int n2 = 0; n2 < 2; ++n2) {
    const int qg2 = qg0 + n2 * 16 + (lane & 15);
    float* op = obase + (size_t)zp * zstride + (size_t)qg2 * DIM;
#pragma unroll
    for (int m2 = 0; m2 < 4; ++m2)
      *(f32x4*)(op + dh * 256 + w * 64 + m2 * 16 + (lane >> 4) * 4) = acc[m2][n2];
  }
}

// ---------------------------------------------------------------------------
// Out[q][d] = (sum_zp Opart[zp][q][d]) / (sum_zp lpart[zp][q]).
// Works in place when obase==Out (JSL==1, zstride==0).
// ---------------------------------------------------------------------------
__global__ __launch_bounds__(256) void k_reduce2(
    const float* __restrict__ obase, size_t zstride, int ZP,
    const float* __restrict__ lpart, float* __restrict__ Out)
{
  const int idx = blockIdx.x * 256 + threadIdx.x;
  const int q = idx >> 7;
  const int d4 = idx & 127;
  const float* p = obase + (size_t)q * DIM + (size_t)d4 * 4;
  f32x4 s = *(const f32x4*)p;
  float l = lpart[q];
  for (int zz = 1; zz < ZP; ++zz) {
    s += *(const f32x4*)(p + (size_t)zz * zstride);
    l += lpart[(size_t)zz * NSEQ + q];
  }
  s *= (1.0f / l);
  *(f32x4*)(Out + (size_t)q * DIM + d4 * 4) = s;
}

// ---------------------------------------------------------------------------
extern "C" void kernel_launch(void* const* d_in, const int* in_sizes, int n_in,
                              void* d_out, int out_size, void* d_ws, size_t ws_size,
                              hipStream_t stream) {
  const float* Wq = (const float*)d_in[0];
  const float* Wk = (const float*)d_in[1];
  const float* X  = (const float*)d_in[2];
  float* Out = (float*)d_out;

  char* w = (char*)d_ws;
  const size_t SPLIT = (size_t)NSEQ * DIM * 2;           // 8 MB
  const size_t XFB   = (size_t)NSEQ * DIM * 2;           // 8 MB frag XhTf
  const size_t WTB   = (size_t)DIM * DIM * 2;            // 512 KB
  const size_t MRPB  = (size_t)128 * NSEQ * 4;           // 4 MB mrowp
  f16* Qh   = (f16*)(w);
  f16* Ql   = (f16*)(w + SPLIT);
  f16* Kh   = (f16*)(w + 2 * SPLIT);
  f16* Kl   = (f16*)(w + 3 * SPLIT);
  f16* XhTf = (f16*)(w + 4 * SPLIT);
  f16* Xh   = (f16*)(w + 4 * SPLIT + XFB);
  f16* Xl   = (f16*)(w + 5 * SPLIT + XFB);
  f16* Wthq = (f16*)(w + 6 * SPLIT + XFB);
  f16* Wtlq = (f16*)(w + 6 * SPLIT + XFB + WTB);
  f16* Wthk = (f16*)(w + 6 * SPLIT + XFB + 2 * WTB);
  f16* Wtlk = (f16*)(w + 6 * SPLIT + XFB + 3 * WTB);
  float* mrow  = (float*)(w + 6 * SPLIT + XFB + 4 * WTB);              // 32 KB
  float* lpart = (float*)(w + 6 * SPLIT + XFB + 4 * WTB + 32768);      // 256 KB
  float* mrowp = (float*)(w + 6 * SPLIT + XFB + 4 * WTB + 327680);     // 4 MB
  const size_t used_base = 6 * SPLIT + XFB + 4 * WTB + 327680 + MRPB;
  char* rest = w + used_base;
  const size_t OPART1 = (size_t)NSEQ * DIM * 4;          // 16 MB per partial
  const size_t avail = (ws_size > used_base) ? ws_size - used_base : 0;

  // pick (CQ, JSL): best measured config {4096,4} first.
  const int cands[8][2] = {{4096,4},{4096,2},{2048,4},{2048,2},
                           {1024,2},{1024,1},{512,1},{256,1}};
  int CQ = 256, JSL = 1;
  for (int c = 0; c < 8; ++c) {
    size_t need = (size_t)cands[c][0] * NSEQ * 4 +
                  (cands[c][1] > 1 ? (size_t)cands[c][1] * OPART1 : 0);
    if (need <= avail) { CQ = cands[c][0]; JSL = cands[c][1]; break; }
  }
  const int gsh = (JSL == 4) ? 3 : (JSL == 2) ? 2 : 1;

  float* ST = (float*)rest;
  float* obase; size_t zstride;
  if (JSL > 1) { obase = (float*)(rest + (size_t)CQ * NSEQ * 4); zstride = (size_t)NSEQ * DIM; }
  else         { obase = Out; zstride = 0; }

  k_splitx<<<NSEQ * DIM / (256 * 4), 256, 0, stream>>>(X, Xh, Xl);
  k_xt2<<<dim3(NSEQ / 64, DIM / 64), 256, 0, stream>>>(X, XhTf);
  k_splitwt2<<<dim3(8, 8, 2), 256, 0, stream>>>(Wq, Wk, Wthq, Wtlq, Wthk, Wtlk);
  k_proj2z<<<dim3(NSEQ / 128, DIM / 128, 2), 256, 0, stream>>>(
      Xh, Xl, Wthq, Wtlq, Wthk, Wtlk, Qh, Ql, Kh, Kl);

  for (int q0 = 0; q0 < NSEQ; q0 += CQ) {
    k_qkt_t<<<dim3(NSEQ / 128, CQ / 128), 256, 0, stream>>>(Kh, Kl, Qh, Ql, ST, mrowp, q0);
    k_smax2<<<dim3(CQ / 256), 256, 0, stream>>>(mrowp, mrow, q0);
    k_pvx4<<<dim3((CQ / 32) << gsh), 256, 0, stream>>>(XhTf, ST, mrow, obase, zstride,
                                                       lpart, q0, NSEQ / JSL, gsh);
  }
  k_reduce2<<<NSEQ * (DIM / 4) / 256, 256, 0, stream>>>(obase, zstride, JSL, lpart, Out);
}